// Round 15
// baseline (117.105 us; speedup 1.0000x reference)
//
#include <hip/hip_runtime.h>
#include <hip/hip_bf16.h>
#include <math.h>

#define NP    261121   // 511*511
#define SPB   256      // px strip per block (conv123)
#define WPX   520      // padded pixel row stride for h2
#define ROWN  4160     // WPX*8 ushorts per plane-row
#define PSTR  2138240  // 514*ROWN ushorts per channel-group plane
#define NBLUR 1041     // blur grid blocks (= partial count)

typedef __attribute__((ext_vector_type(8))) short short8;
typedef __attribute__((ext_vector_type(4))) float f32x4;
typedef __attribute__((ext_vector_type(4), aligned(4))) float f32x4a;

static __device__ __forceinline__ unsigned short f2bf(float f) {
    unsigned int u = __builtin_bit_cast(unsigned int, f);
    u += 0x7FFFu + ((u >> 16) & 1u);   // round-to-nearest-even
    return (unsigned short)(u >> 16);
}

static __device__ __forceinline__ short bf16s(float f) {
    __hip_bfloat16 h = __float2bfloat16(f);   // HW cvt, RNE
    return __builtin_bit_cast(short, h);
}

// direct global->LDS DMA, 16B per lane (dest = uniform base + lane*16)
static __device__ __forceinline__ void gl_lds16(const float* g, float* l) {
    __builtin_amdgcn_global_load_lds(
        (const __attribute__((address_space(1))) unsigned int*)g,
        (__attribute__((address_space(3))) unsigned int*)l,
        16, 0, 0);
}

// ---------------- K1: fused 1x1 convs 204->16->8->1 via MFMA ----------------
// Staging via global_load_lds (no VGPR round-trip): per k-step, 32 channel
// rows of 1KB each stage directly into LDS f32; compute phase does
// ds_read_b128 + cvt->bf16 + MFMA. Double-buffered, barrier-drained (vmcnt).
__global__ __launch_bounds__(256, 2) void k_conv123(const float* __restrict__ x,
                                                    const float* __restrict__ w_x1,
                                                    const float* __restrict__ b1,
                                                    const float* __restrict__ w2,
                                                    const float* __restrict__ b2,
                                                    const float* __restrict__ w3,
                                                    const float* __restrict__ b3,
                                                    float* __restrict__ tmp12)
{
    __shared__ float sb[2 * 32 * 256];   // 64 KB: 2 x [32ch][256px] f32

    const int tid = threadIdx.x;
    const int v = tid >> 6, l = tid & 63;
    const int lpx = l & 15, kg = l >> 4;
    int pxb = blockIdx.x * SPB;
    if (pxb > NP - SPB) pxb = NP - SPB;   // overlap tail (identical recompute)

    // A-frags: afr[ks][j] = bf16(W[o=lpx][c=ks*32+kg*8+j]), K zero-padded 204->224
    short8 afr[7];
    {
        const float* wrow = w_x1 + lpx * 204;
#pragma unroll
        for (int ks = 0; ks < 7; ++ks)
#pragma unroll
            for (int j = 0; j < 8; ++j) {
                int c = ks * 32 + kg * 8 + j;
                afr[ks][j] = (short)f2bf(c < 204 ? wrow[c] : 0.f);
            }
    }

    f32x4 acc[4];
#pragma unroll
    for (int n = 0; n < 4; ++n) acc[n] = (f32x4){0.f, 0.f, 0.f, 0.f};

    // wave v stages channels v*8..v*8+7 of k-step KS (1KB row = 1 gload_lds)
#define STAGE(KS) do { \
        _Pragma("unroll") \
        for (int i = 0; i < 8; ++i) { \
            const int ch = v * 8 + i; \
            const float* src = ((KS) < 6 || ch < 12) \
                ? x + (size_t)((KS) * 32 + ch) * NP + pxb + 4 * l \
                : x + pxb + 4 * l;   /* finite dummy, weight = 0 */ \
            gl_lds16(src, sb + ((KS) & 1) * 8192 + ch * 256); \
        } \
    } while (0)

    // compute k-step KS: 8 ds_read_b128 (f32) + 32 cvt + 4 MFMA per lane
#define COMPUTE(KS) do { \
        const float* base = sb + ((KS) & 1) * 8192 + (kg * 8) * 256 + v * 64 + lpx * 4; \
        f32x4 r0 = *reinterpret_cast<const f32x4*>(base); \
        f32x4 r1 = *reinterpret_cast<const f32x4*>(base + 256); \
        f32x4 r2 = *reinterpret_cast<const f32x4*>(base + 512); \
        f32x4 r3 = *reinterpret_cast<const f32x4*>(base + 768); \
        f32x4 r4 = *reinterpret_cast<const f32x4*>(base + 1024); \
        f32x4 r5 = *reinterpret_cast<const f32x4*>(base + 1280); \
        f32x4 r6 = *reinterpret_cast<const f32x4*>(base + 1536); \
        f32x4 r7 = *reinterpret_cast<const f32x4*>(base + 1792); \
        _Pragma("unroll") \
        for (int n = 0; n < 4; ++n) { \
            short8 b; \
            b[0] = bf16s(r0[n]); b[1] = bf16s(r1[n]); \
            b[2] = bf16s(r2[n]); b[3] = bf16s(r3[n]); \
            b[4] = bf16s(r4[n]); b[5] = bf16s(r5[n]); \
            b[6] = bf16s(r6[n]); b[7] = bf16s(r7[n]); \
            acc[n] = __builtin_amdgcn_mfma_f32_16x16x32_bf16(afr[KS], b, acc[n], 0, 0, 0); \
        } \
    } while (0)

    STAGE(0);
#define STEP(K, LAST) do { \
        __syncthreads(); \
        if (!(LAST)) STAGE((K) + 1); \
        COMPUTE(K); \
    } while (0)

    STEP(0, 0); STEP(1, 0); STEP(2, 0); STEP(3, 0); STEP(4, 0); STEP(5, 0); STEP(6, 1);
#undef STAGE
#undef COMPUTE
#undef STEP

    // epilogue: lane holds f1-preact[o=kg*4+r][px = pxb + v*64 + lpx*4 + n]
    float4 b1v = *reinterpret_cast<const float4*>(b1 + kg * 4);
    float4 w2v[8];
#pragma unroll
    for (int j = 0; j < 8; ++j)
        w2v[j] = *reinterpret_cast<const float4*>(w2 + j * 16 + kg * 4);
    float b2v[8], w3v[8];
#pragma unroll
    for (int j = 0; j < 8; ++j) { b2v[j] = b2[j]; w3v[j] = w3[j]; }
    float b3v = b3[0];

    f32x4 resv;
#pragma unroll
    for (int n = 0; n < 4; ++n) {
        float f0 = fmaxf(acc[n][0] + b1v.x, 0.f);
        float f1 = fmaxf(acc[n][1] + b1v.y, 0.f);
        float f2 = fmaxf(acc[n][2] + b1v.z, 0.f);
        float f3 = fmaxf(acc[n][3] + b1v.w, 0.f);
        float tmp = b3v;
#pragma unroll
        for (int j = 0; j < 8; ++j) {
            float sj = f0 * w2v[j].x;
            sj = fmaf(f1, w2v[j].y, sj);
            sj = fmaf(f2, w2v[j].z, sj);
            sj = fmaf(f3, w2v[j].w, sj);
            sj += __shfl_xor(sj, 16, 64);
            sj += __shfl_xor(sj, 32, 64);
            tmp = fmaf(fmaxf(sj + b2v[j], 0.f), w3v[j], tmp);
        }
        resv[n] = fmaxf(tmp, 0.f);
    }
    if (kg == 0)
        *reinterpret_cast<f32x4a*>(tmp12 + pxb + v * 64 + lpx * 4) = resv;
}

// ------ K2: Haar DWT + 1x1 conv(pad=1) + pixel_shuffle; also wb2 + h2 ring --
__global__ __launch_bounds__(256) void k_dwt(const float* __restrict__ tmp12,
                                             const float* __restrict__ w_hi,
                                             const float* __restrict__ b_hi,
                                             const float* __restrict__ w_c9b,
                                             float* __restrict__ hf,
                                             unsigned short* __restrict__ wb2,
                                             unsigned short* __restrict__ h2)
{
    int t = blockIdx.x * 256 + threadIdx.x;

    if (t < 18432) {
        int o = t / 288, ck = t - o * 288;
        int c = ck / 9, k = ck - c * 9;
        wb2[k * 2048 + o * 32 + c] = f2bf(w_c9b[t]);
    }
    short8 z8 = {0, 0, 0, 0, 0, 0, 0, 0};
    if (t < 4160) {
        int pl = t / 1040;
        int rr = t - pl * 1040;
        int row = rr >= 520 ? 512 : 0;
        int ch  = rr >= 520 ? rr - 520 : rr;
        *reinterpret_cast<short8*>(h2 + (size_t)pl * PSTR + (size_t)row * ROWN + ch * 8) = z8;
    }
    int z = t - 4160;
    if (z >= 0 && z < 6132) {
        int row = z / 12 + 1;
        int j = z - (row - 1) * 12;
        int pl = j / 3, cidx = j - pl * 3;
        int col = (cidx == 0) ? 0 : (cidx == 1 ? 512 : 513);
        *reinterpret_cast<short8*>(h2 + (size_t)pl * PSTR + (size_t)row * ROWN + col * 8) = z8;
    }

    const float INV = 0.70710678118654752440f;
    if (t >= 258 * 258) return;
    int h = t / 258, w = t - h * 258;

    float wh[12], bh[4];
#pragma unroll
    for (int i = 0; i < 12; ++i) wh[i] = w_hi[i];
#pragma unroll
    for (int o = 0; o < 4; ++o) bh[o] = b_hi[o];

    float v[4];
    if (h == 0 || h == 257 || w == 0 || w == 257) {
#pragma unroll
        for (int o = 0; o < 4; ++o) v[o] = fmaxf(bh[o], 0.f);
    } else {
        int hh = h - 1, ww = w - 1;
        int r0 = 2 * hh, r1 = 2 * hh + 1, c0 = 2 * ww, c1 = 2 * ww + 1;
        float a = tmp12[r0 * 511 + c0];
        float b = (c1 < 511) ? tmp12[r0 * 511 + c1] : 0.f;
        float c = (r1 < 511) ? tmp12[r1 * 511 + c0] : 0.f;
        float d = (r1 < 511 && c1 < 511) ? tmp12[r1 * 511 + c1] : 0.f;
        float lo0 = (a + b) * INV, hi0 = (a - b) * INV;
        float lo1 = (c + d) * INV, hi1 = (c - d) * INV;
        float cH = (lo0 - lo1) * INV;
        float cV = (hi0 + hi1) * INV;
        float cD = (hi0 - hi1) * INV;
#pragma unroll
        for (int o = 0; o < 4; ++o)
            v[o] = fmaxf(wh[o * 3 + 0] * cH + wh[o * 3 + 1] * cV + wh[o * 3 + 2] * cD + bh[o], 0.f);
    }
    int orow = (2 * h) * 516 + 2 * w;
    hf[orow]       = v[0];
    hf[orow + 1]   = v[1];
    hf[orow + 516] = v[2];
    hf[orow + 517] = v[3];
}

// ------- K3: 5x5 separable gaussian blur (reflect) + per-block partials -----
__global__ __launch_bounds__(256) void k_blur(const float* __restrict__ hf,
                                              float* __restrict__ hfb,
                                              float* __restrict__ psum,
                                              float* __restrict__ pmax,
                                              float g0, float g1, float g2)
{
    __shared__ float ss[256], sm[256];
    int t = threadIdx.x;
    int idx = blockIdx.x * 256 + t;
    bool ok = idx < 516 * 516;
    int idc = ok ? idx : 0;
    int y = idc / 516, x = idc - y * 516;
    float g[5] = {g0, g1, g2, g1, g0};
    int ry[5], rx[5];
#pragma unroll
    for (int i = 0; i < 5; ++i) {
        int yy = y + i - 2; yy = yy < 0 ? -yy : (yy > 515 ? 1030 - yy : yy);
        int xx = x + i - 2; xx = xx < 0 ? -xx : (xx > 515 ? 1030 - xx : xx);
        ry[i] = yy * 516; rx[i] = xx;
    }
    float s = 0.f;
#pragma unroll
    for (int i = 0; i < 5; ++i) {
        float rs = 0.f;
#pragma unroll
        for (int j = 0; j < 5; ++j) rs = fmaf(g[j], hf[ry[i] + rx[j]], rs);
        s = fmaf(g[i], rs, s);
    }
    if (ok) hfb[idx] = s;

    ss[t] = ok ? s : 0.f;
    sm[t] = ok ? s : -3.4e38f;
    __syncthreads();
    for (int off = 128; off > 0; off >>= 1) {
        if (t < off) { ss[t] += ss[t + off]; sm[t] = fmaxf(sm[t], sm[t + off]); }
        __syncthreads();
    }
    if (t == 0) { psum[blockIdx.x] = ss[0]; pmax[blockIdx.x] = sm[0]; }
}

// --- K5: final reduce -> sigmoid gate + 6x6 valid conv + bias+relu+residual -
__global__ __launch_bounds__(256) void k_cat(const float* __restrict__ hfb,
                                             const float* __restrict__ tmp12,
                                             const float* __restrict__ psum,
                                             const float* __restrict__ pmax,
                                             const float* __restrict__ caw1,
                                             const float* __restrict__ caw2,
                                             const float* __restrict__ w_cat,
                                             const float* __restrict__ b_cat,
                                             float* __restrict__ f12)
{
    __shared__ float ss[256], sm[256], ssc;
    int t = threadIdx.x;
    {
        float s = 0.f, m = -3.4e38f;
        for (int i = t; i < NBLUR; i += 256) { s += psum[i]; m = fmaxf(m, pmax[i]); }
        ss[t] = s; sm[t] = m;
        __syncthreads();
        for (int off = 128; off > 0; off >>= 1) {
            if (t < off) { ss[t] += ss[t + off]; sm[t] = fmaxf(sm[t], sm[t + off]); }
            __syncthreads();
        }
        if (t == 0) {
            float avg = ss[0] / 266256.f;
            float a = caw1[0], b = caw2[0];
            float z = b * fmaxf(a * avg, 0.f) + b * fmaxf(a * sm[0], 0.f);
            ssc = 1.f / (1.f + expf(-z));
        }
        __syncthreads();
    }
    float sc = ssc;

    int p = blockIdx.x * 256 + t;
    if (p >= NP) return;
    int y = p / 511, x = p - y * 511;
    float s = 0.f;
#pragma unroll
    for (int ky = 0; ky < 6; ++ky) {
        const float* row = hfb + (y + ky) * 516 + x;
#pragma unroll
        for (int kx = 0; kx < 6; ++kx) s = fmaf(row[kx], w_cat[ky * 6 + kx], s);
    }
    f12[p] = tmp12[p] + fmaxf(sc * s + b_cat[0], 0.f);
}

// ---------------- K6: 3x3 conv 1->32, pad 1, relu -> bf16 4-plane h2 --------
__global__ __launch_bounds__(256) void k_c9a(const float* __restrict__ f12,
                                             const float* __restrict__ w_c9a,
                                             const float* __restrict__ bias,
                                             unsigned short* __restrict__ h2)
{
    int p = blockIdx.x * 256 + threadIdx.x;
    if (p >= NP) return;
    int y = p / 511, x = p - y * 511;
    float hv[9];
#pragma unroll
    for (int ky = 0; ky < 3; ++ky)
#pragma unroll
        for (int kx = 0; kx < 3; ++kx) {
            int yy = y + ky - 1, xx = x + kx - 1;
            hv[ky * 3 + kx] = (yy >= 0 && yy < 511 && xx >= 0 && xx < 511) ? f12[yy * 511 + xx] : 0.f;
        }
    float acc[32];
#pragma unroll
    for (int o = 0; o < 32; ++o) acc[o] = bias[o];
#pragma unroll
    for (int k = 0; k < 9; ++k) {
        float v = hv[k];
#pragma unroll
        for (int o = 0; o < 32; ++o) acc[o] = fmaf(v, w_c9a[o * 9 + k], acc[o]);
    }
    unsigned short o16[32];
#pragma unroll
    for (int o = 0; o < 32; ++o) o16[o] = f2bf(fmaxf(acc[o], 0.f));
    size_t px = (size_t)(y + 1) * WPX + (x + 1);
#pragma unroll
    for (int i = 0; i < 4; ++i)
        *reinterpret_cast<short8*>(h2 + (size_t)i * PSTR + px * 8) =
            reinterpret_cast<const short8*>(o16)[i];
}

// ---------------- K7: 3x3 conv 32->64, MFMA, LDS weights, 2-ahead pipeline --
__global__ __launch_bounds__(256, 3) void k_c9b(const unsigned short* __restrict__ h2,
                                                const unsigned short* __restrict__ wb2,
                                                const float* __restrict__ bias,
                                                float* __restrict__ out)
{
    __shared__ unsigned short swu[9 * 2048];

    int bid = blockIdx.x;
    int xcd = bid & 7, jj = bid >> 3;
    const int q = 127, r = 6;
    int wg = (xcd < r ? xcd * (q + 1) : r * (q + 1) + (xcd - r) * q) + jj;

    int lane = threadIdx.x & 63;
    int wave = threadIdx.x >> 6;
    int y  = wg >> 1;
    int xh = wg & 1;
    int xb = xh * 256 + wave * 64;
    int lpx = lane & 15, kg = lane >> 4;

    {
        const short8* wsrc = reinterpret_cast<const short8*>(wb2);
        short8* wdst = reinterpret_cast<short8*>(swu);
        for (int d = threadIdx.x; d < 2304; d += 256) {
            int kt = d >> 8, rem = d & 255, m = rem >> 6, l = rem & 63;
            wdst[d] = wsrc[kt * 256 + (m * 16 + (l & 15)) * 4 + (l >> 4)];
        }
    }
    __syncthreads();

    f32x4 acc[4][4];
#pragma unroll
    for (int m = 0; m < 4; ++m)
#pragma unroll
        for (int n = 0; n < 4; ++n) acc[m][n] = (f32x4){0.f, 0.f, 0.f, 0.f};

    const unsigned short* hb = h2 + (size_t)kg * PSTR;
    const int base_px = (y + 1) * WPX + (xb + 1) + lpx;
    const int rowm = base_px - WPX, row0 = base_px, rowp = base_px + WPX;
    const short8* swv = reinterpret_cast<const short8*>(swu);

#define LOADB(BUF, ROW, DX) do { \
        const unsigned short* rp = hb + (size_t)((ROW) + (DX)) * 8; \
        BUF[0] = *reinterpret_cast<const short8*>(rp); \
        BUF[1] = *reinterpret_cast<const short8*>(rp + 128); \
        BUF[2] = *reinterpret_cast<const short8*>(rp + 256); \
        BUF[3] = *reinterpret_cast<const short8*>(rp + 384); \
    } while (0)

#define TAP(KT, BUF) do { \
        const short8* ap = swv + (KT) * 256 + lane; \
        short8 a0 = ap[0], a1 = ap[64], a2 = ap[128], a3 = ap[192]; \
        _Pragma("unroll") \
        for (int n = 0; n < 4; ++n) { \
            acc[0][n] = __builtin_amdgcn_mfma_f32_16x16x32_bf16(a0, BUF[n], acc[0][n], 0, 0, 0); \
            acc[1][n] = __builtin_amdgcn_mfma_f32_16x16x32_bf16(a1, BUF[n], acc[1][n], 0, 0, 0); \
            acc[2][n] = __builtin_amdgcn_mfma_f32_16x16x32_bf16(a2, BUF[n], acc[2][n], 0, 0, 0); \
            acc[3][n] = __builtin_amdgcn_mfma_f32_16x16x32_bf16(a3, BUF[n], acc[3][n], 0, 0, 0); \
        } \
    } while (0)

    short8 bX[4], bY[4], bZ[4];
    LOADB(bX, rowm, -1);
    LOADB(bY, rowm,  0);
    LOADB(bZ, rowm, +1); TAP(0, bX);
    LOADB(bX, row0, -1); TAP(1, bY);
    LOADB(bY, row0,  0); TAP(2, bZ);
    LOADB(bZ, row0, +1); TAP(3, bX);
    LOADB(bX, rowp, -1); TAP(4, bY);
    LOADB(bY, rowp,  0); TAP(5, bZ);
    LOADB(bZ, rowp, +1); TAP(6, bX);
    TAP(7, bY);
    TAP(8, bZ);
#undef LOADB
#undef TAP

    const int ybase = y * 511;
#pragma unroll
    for (int m = 0; m < 4; ++m) {
#pragma unroll
        for (int rr = 0; rr < 4; ++rr) {
            int o = m * 16 + kg * 4 + rr;
            float bo = bias[o];
#pragma unroll
            for (int n = 0; n < 4; ++n) {
                int px = xb + n * 16 + lpx;
                if (px < 511)
                    out[(size_t)o * NP + ybase + px] = fmaxf(acc[m][n][rr] + bo, 0.f);
            }
        }
    }
}

// ---------------------------------------------------------------------------
extern "C" void kernel_launch(void* const* d_in, const int* in_sizes, int n_in,
                              void* d_out, int out_size, void* d_ws, size_t ws_size,
                              hipStream_t stream)
{
    (void)in_sizes; (void)n_in; (void)out_size; (void)ws_size;

    const float* x     = (const float*)d_in[0];
    const float* w_x1  = (const float*)d_in[1];
    const float* b_x1  = (const float*)d_in[2];
    const float* w_x2  = (const float*)d_in[3];
    const float* b_x2  = (const float*)d_in[4];
    const float* w_x3  = (const float*)d_in[5];
    const float* b_x3  = (const float*)d_in[6];
    const float* w_hi  = (const float*)d_in[7];
    const float* b_hi  = (const float*)d_in[8];
    const float* ca1w1 = (const float*)d_in[11];
    const float* ca1w2 = (const float*)d_in[12];
    const float* w_cat = (const float*)d_in[15];
    const float* b_cat = (const float*)d_in[16];
    const float* w_c9a = (const float*)d_in[17];
    const float* b_c9a = (const float*)d_in[18];
    const float* w_c9b = (const float*)d_in[19];
    const float* b_c9b = (const float*)d_in[20];

    float* ws    = (float*)d_ws;
    float* tmp12 = ws + 0;                       // 261184
    float* hf    = ws + 261184;                  // 266304
    float* hfb   = ws + 527488;                  // 266304
    float* f12   = ws + 793792;                  // 261184
    float* psum  = ws + 1054976;                 // 1056
    float* pmax  = ws + 1056032;                 // 1056
    unsigned short* wb2 = (unsigned short*)(ws + 1057088);   // 18432 ushorts
    unsigned short* h2  = (unsigned short*)(ws + 1066304);   // 4*PSTR ushorts

    float* out = (float*)d_out;

    double kk[5], ssum = 0.0;
    for (int i = 0; i < 5; ++i) { double r = i - 2.0; kk[i] = exp(-r * r / 0.5); ssum += kk[i]; }
    float g0 = (float)(kk[0] / ssum), g1 = (float)(kk[1] / ssum), g2 = (float)(kk[2] / ssum);

    k_conv123<<<1021, 256, 0, stream>>>(x, w_x1, b_x1, w_x2, b_x2, w_x3, b_x3, tmp12);
    k_dwt<<<261, 256, 0, stream>>>(tmp12, w_hi, b_hi, w_c9b, hf, wb2, h2);
    k_blur<<<NBLUR, 256, 0, stream>>>(hf, hfb, psum, pmax, g0, g1, g2);
    k_cat<<<1021, 256, 0, stream>>>(hfb, tmp12, psum, pmax, ca1w1, ca1w2, w_cat, b_cat, f12);
    k_c9a<<<1021, 256, 0, stream>>>(f12, w_c9a, b_c9a, h2);
    k_c9b<<<1022, 256, 0, stream>>>(h2, wb2, b_c9b, out);
}

// Round 16
// 98.924 us; speedup vs baseline: 1.1838x; 1.1838x over previous
//
#include <hip/hip_runtime.h>
#include <hip/hip_bf16.h>
#include <math.h>

#define NP    261121   // 511*511
#define SPB   512      // px strip per block (conv123)
#define RS    520      // conv123 LDS row stride in ushorts
#define OFS   16640    // 32*RS ushorts per LDS buffer
#define WPX   520      // padded pixel row stride for h2
#define ROWN  4160     // WPX*8 ushorts per plane-row
#define PSTR  2138240  // 514*ROWN ushorts per channel-group plane
#define NBP   289      // dwtblur grid blocks (17x17) = partial count

typedef __attribute__((ext_vector_type(8))) short short8;
typedef __attribute__((ext_vector_type(4))) short short4v;
typedef __attribute__((ext_vector_type(4))) float f32x4;
typedef __attribute__((ext_vector_type(4), aligned(4))) float f32x4a;

static __device__ __forceinline__ unsigned short f2bf(float f) {
    unsigned int u = __builtin_bit_cast(unsigned int, f);
    u += 0x7FFFu + ((u >> 16) & 1u);   // round-to-nearest-even
    return (unsigned short)(u >> 16);
}

static __device__ __forceinline__ short bf16s(float f) {
    __hip_bfloat16 h = __float2bfloat16(f);   // HW cvt, RNE
    return __builtin_bit_cast(short, h);
}

// ---------------- K1: fused 1x1 convs 204->16->8->1 (R13 structure) --------
// + side duties: wb2 weight pack and h2 pad-ring zero (t < 18432 threads).
__global__ __launch_bounds__(256, 2) void k_conv123(const float* __restrict__ x,
                                                    const float* __restrict__ w_x1,
                                                    const float* __restrict__ b1,
                                                    const float* __restrict__ w2,
                                                    const float* __restrict__ b2,
                                                    const float* __restrict__ w3,
                                                    const float* __restrict__ b3,
                                                    const float* __restrict__ w_c9b,
                                                    float* __restrict__ tmp12,
                                                    unsigned short* __restrict__ wb2,
                                                    unsigned short* __restrict__ h2)
{
    // ---- side duties (first 73 blocks only) ----
    {
        int t = blockIdx.x * 256 + threadIdx.x;
        if (t < 18432) {
            int o = t / 288, ck = t - o * 288;
            int c = ck / 9, k = ck - c * 9;
            wb2[k * 2048 + o * 32 + c] = f2bf(w_c9b[t]);
        }
        short8 z8 = {0, 0, 0, 0, 0, 0, 0, 0};
        if (t < 4160) {
            int pl = t / 1040;
            int rr = t - pl * 1040;
            int row = rr >= 520 ? 512 : 0;
            int ch  = rr >= 520 ? rr - 520 : rr;
            *reinterpret_cast<short8*>(h2 + (size_t)pl * PSTR + (size_t)row * ROWN + ch * 8) = z8;
        }
        int z = t - 4160;
        if (z >= 0 && z < 6132) {
            int row = z / 12 + 1;
            int j = z - (row - 1) * 12;
            int pl = j / 3, cidx = j - pl * 3;
            int col = (cidx == 0) ? 0 : (cidx == 1 ? 512 : 513);
            *reinterpret_cast<short8*>(h2 + (size_t)pl * PSTR + (size_t)row * ROWN + col * 8) = z8;
        }
    }

    __shared__ unsigned short sb[2 * OFS];   // 65 KB: 2 x [32ch][520] bf16

    const int tid = threadIdx.x;
    const int v = tid >> 6, l = tid & 63;
    const int lpx = l & 15, kg = l >> 4;
    int pxb = blockIdx.x * SPB;
    if (pxb > NP - SPB) pxb = NP - SPB;

    short8 afr[7];
    {
        const float* wrow = w_x1 + lpx * 204;
#pragma unroll
        for (int ks = 0; ks < 7; ++ks)
#pragma unroll
            for (int j = 0; j < 8; ++j) {
                int c = ks * 32 + kg * 8 + j;
                afr[ks][j] = (short)f2bf(c < 204 ? wrow[c] : 0.f);
            }
    }

    const float* xb = x + pxb + 4 * l;
    const float* lpB[8];
#pragma unroll
    for (int i = 0; i < 8; ++i)
        lpB[i] = xb + (size_t)(v * 8 + i) * NP;

    f32x4 acc[8];
#pragma unroll
    for (int n = 0; n < 8; ++n) acc[n] = (f32x4){0.f, 0.f, 0.f, 0.f};

    f32x4a q0[8], q1[8];

#define LOADISSUE(KS) do { \
        _Pragma("unroll") \
        for (int i = 0; i < 8; ++i) { \
            const float* p = ((KS) < 6 || v * 8 + i < 12) ? lpB[i] + (size_t)(KS) * 32 * NP : xb; \
            q0[i] = *reinterpret_cast<const f32x4a*>(p); \
            q1[i] = *reinterpret_cast<const f32x4a*>(p + 256); \
        } \
    } while (0)

#define CVTWRITE(BUF) do { \
        _Pragma("unroll") \
        for (int i = 0; i < 8; ++i) { \
            unsigned short* row = sb + (BUF) * OFS + (v * 8 + i) * RS; \
            short4v w0, w1; \
            _Pragma("unroll") \
            for (int n = 0; n < 4; ++n) { w0[n] = bf16s(q0[i][n]); w1[n] = bf16s(q1[i][n]); } \
            *reinterpret_cast<short4v*>(row + 4 * l)       = w0; \
            *reinterpret_cast<short4v*>(row + 256 + 4 * l) = w1; \
        } \
    } while (0)

#define COMPUTE(KS, BUF) do { \
        short8 r0, r1, r2, r3, r4, r5, r6, r7; \
        const unsigned short* base = sb + (BUF) * OFS + kg * 8 * RS + v * 128 + lpx * 8; \
        r0 = *reinterpret_cast<const short8*>(base); \
        r1 = *reinterpret_cast<const short8*>(base + RS); \
        r2 = *reinterpret_cast<const short8*>(base + 2 * RS); \
        r3 = *reinterpret_cast<const short8*>(base + 3 * RS); \
        r4 = *reinterpret_cast<const short8*>(base + 4 * RS); \
        r5 = *reinterpret_cast<const short8*>(base + 5 * RS); \
        r6 = *reinterpret_cast<const short8*>(base + 6 * RS); \
        r7 = *reinterpret_cast<const short8*>(base + 7 * RS); \
        _Pragma("unroll") \
        for (int n = 0; n < 8; ++n) { \
            short8 b; \
            b[0] = r0[n]; b[1] = r1[n]; b[2] = r2[n]; b[3] = r3[n]; \
            b[4] = r4[n]; b[5] = r5[n]; b[6] = r6[n]; b[7] = r7[n]; \
            acc[n] = __builtin_amdgcn_mfma_f32_16x16x32_bf16(afr[KS], b, acc[n], 0, 0, 0); \
        } \
    } while (0)

    LOADISSUE(0);
    CVTWRITE(0);

#define STEP(K, LAST) do { \
        if (!(LAST)) LOADISSUE((K) + 1); \
        __syncthreads(); \
        COMPUTE((K), (K) & 1); \
        if (!(LAST)) CVTWRITE(((K) + 1) & 1); \
    } while (0)

    STEP(0, 0); STEP(1, 0); STEP(2, 0); STEP(3, 0); STEP(4, 0); STEP(5, 0); STEP(6, 1);
#undef LOADISSUE
#undef CVTWRITE
#undef COMPUTE
#undef STEP

    float4 b1v = *reinterpret_cast<const float4*>(b1 + kg * 4);
    float4 w2v[8];
#pragma unroll
    for (int j = 0; j < 8; ++j)
        w2v[j] = *reinterpret_cast<const float4*>(w2 + j * 16 + kg * 4);
    float b2v[8], w3v[8];
#pragma unroll
    for (int j = 0; j < 8; ++j) { b2v[j] = b2[j]; w3v[j] = w3[j]; }
    float b3v = b3[0];

    f32x4 rlo, rhi;
#pragma unroll
    for (int n = 0; n < 8; ++n) {
        float f0 = fmaxf(acc[n][0] + b1v.x, 0.f);
        float f1 = fmaxf(acc[n][1] + b1v.y, 0.f);
        float f2 = fmaxf(acc[n][2] + b1v.z, 0.f);
        float f3 = fmaxf(acc[n][3] + b1v.w, 0.f);
        float tmp = b3v;
#pragma unroll
        for (int j = 0; j < 8; ++j) {
            float sj = f0 * w2v[j].x;
            sj = fmaf(f1, w2v[j].y, sj);
            sj = fmaf(f2, w2v[j].z, sj);
            sj = fmaf(f3, w2v[j].w, sj);
            sj += __shfl_xor(sj, 16, 64);
            sj += __shfl_xor(sj, 32, 64);
            tmp = fmaf(fmaxf(sj + b2v[j], 0.f), w3v[j], tmp);
        }
        if (n < 4) rlo[n] = fmaxf(tmp, 0.f);
        else       rhi[n - 4] = fmaxf(tmp, 0.f);
    }
    if (kg == 0) {
        float* dst = tmp12 + pxb + v * 128 + lpx * 8;
        *reinterpret_cast<f32x4a*>(dst)     = rlo;
        *reinterpret_cast<f32x4a*>(dst + 4) = rhi;
    }
}

// ----- K2: fused DWT + hi-1x1 + pixel_shuffle + 5x5 blur + gate partials ----
// 32x32 hfb tile per block; hf lives only in LDS (36x37 tile incl. 2-halo).
__global__ __launch_bounds__(256) void k_dwtblur(const float* __restrict__ tmp12,
                                                 const float* __restrict__ w_hi,
                                                 const float* __restrict__ b_hi,
                                                 float* __restrict__ hfb,
                                                 float* __restrict__ psum,
                                                 float* __restrict__ pmax,
                                                 float g0, float g1, float g2)
{
    __shared__ float hfT[36][37];
    __shared__ float ss[256], sm[256];
    const float INV = 0.70710678118654752440f;

    int tid = threadIdx.x;
    int bx = blockIdx.x % 17, by = blockIdx.x / 17;
    int X0 = bx * 32, Y0 = by * 32;
    int Ylo = Y0 - 2 < 0 ? 0 : Y0 - 2;
    int Yhi = Y0 + 33 > 515 ? 515 : Y0 + 33;
    int Xlo = X0 - 2 < 0 ? 0 : X0 - 2;
    int Xhi = X0 + 33 > 515 ? 515 : X0 + 33;
    int hlo = Ylo >> 1, hhi = Yhi >> 1, nh = hhi - hlo + 1;
    int wlo = Xlo >> 1, whi = Xhi >> 1, nw = whi - wlo + 1;
    int ncells = nh * nw;

    float wh[12], bh[4];
#pragma unroll
    for (int i = 0; i < 12; ++i) wh[i] = w_hi[i];
#pragma unroll
    for (int o = 0; o < 4; ++o) bh[o] = b_hi[o];

    for (int ci = tid; ci < ncells; ci += 256) {
        int h = hlo + ci / nw, w = wlo + ci % nw;
        float v[4];
        if (h == 0 || h == 257 || w == 0 || w == 257) {
#pragma unroll
            for (int o = 0; o < 4; ++o) v[o] = fmaxf(bh[o], 0.f);
        } else {
            int hh = h - 1, ww = w - 1;
            int r0 = 2 * hh, r1 = 2 * hh + 1, c0 = 2 * ww, c1 = 2 * ww + 1;
            float a = tmp12[r0 * 511 + c0];
            float b = (c1 < 511) ? tmp12[r0 * 511 + c1] : 0.f;
            float c = (r1 < 511) ? tmp12[r1 * 511 + c0] : 0.f;
            float d = (r1 < 511 && c1 < 511) ? tmp12[r1 * 511 + c1] : 0.f;
            float lo0 = (a + b) * INV, hi0 = (a - b) * INV;
            float lo1 = (c + d) * INV, hi1 = (c - d) * INV;
            float cH = (lo0 - lo1) * INV;
            float cV = (hi0 + hi1) * INV;
            float cD = (hi0 - hi1) * INV;
#pragma unroll
            for (int o = 0; o < 4; ++o)
                v[o] = fmaxf(wh[o * 3 + 0] * cH + wh[o * 3 + 1] * cV + wh[o * 3 + 2] * cD + bh[o], 0.f);
        }
#pragma unroll
        for (int dy = 0; dy < 2; ++dy)
#pragma unroll
            for (int dx = 0; dx < 2; ++dx) {
                int Y = 2 * h + dy, X = 2 * w + dx;
                if (Y >= Ylo && Y <= Yhi && X >= Xlo && X <= Xhi)
                    hfT[Y - Y0 + 2][X - X0 + 2] = v[dy * 2 + dx];
            }
    }
    __syncthreads();

    float g[5] = {g0, g1, g2, g1, g0};
    float lsum = 0.f, lmax = -3.4e38f;
#pragma unroll
    for (int k2 = 0; k2 < 4; ++k2) {
        int o = tid + k2 * 256;
        int oy = o >> 5, ox = o & 31;
        int gy = Y0 + oy, gx = X0 + ox;
        if (gy < 516 && gx < 516) {
            int ly[5], lx[5];
#pragma unroll
            for (int i = 0; i < 5; ++i) {
                int yy = gy + i - 2; yy = yy < 0 ? -yy : (yy > 515 ? 1030 - yy : yy);
                int xx = gx + i - 2; xx = xx < 0 ? -xx : (xx > 515 ? 1030 - xx : xx);
                ly[i] = yy - Y0 + 2; lx[i] = xx - X0 + 2;
            }
            float s = 0.f;
#pragma unroll
            for (int i = 0; i < 5; ++i) {
                float rs = 0.f;
#pragma unroll
                for (int j = 0; j < 5; ++j) rs = fmaf(g[j], hfT[ly[i]][lx[j]], rs);
                s = fmaf(g[i], rs, s);
            }
            hfb[gy * 516 + gx] = s;
            lsum += s; lmax = fmaxf(lmax, s);
        }
    }

    ss[tid] = lsum; sm[tid] = lmax;
    __syncthreads();
    for (int off = 128; off > 0; off >>= 1) {
        if (tid < off) { ss[tid] += ss[tid + off]; sm[tid] = fmaxf(sm[tid], sm[tid + off]); }
        __syncthreads();
    }
    if (tid == 0) { psum[blockIdx.x] = ss[0]; pmax[blockIdx.x] = sm[0]; }
}

// ----- K3: gate reduce + 6x6 cat conv + residual (f12 in LDS) + 3x3 c9a -----
// 16x16 h2-output tile per block; f12 lives only in LDS (18x19 incl. 1-halo).
__global__ __launch_bounds__(256) void k_catc9a(const float* __restrict__ hfb,
                                                const float* __restrict__ tmp12,
                                                const float* __restrict__ psum,
                                                const float* __restrict__ pmax,
                                                const float* __restrict__ caw1,
                                                const float* __restrict__ caw2,
                                                const float* __restrict__ w_cat,
                                                const float* __restrict__ b_cat,
                                                const float* __restrict__ w_c9a,
                                                const float* __restrict__ bias9a,
                                                unsigned short* __restrict__ h2)
{
    __shared__ float f12T[18][19];
    __shared__ float ss[256], sm[256];
    __shared__ float ssc;
    int tid = threadIdx.x;

    {   // gate: redundant per-block reduce of the 289 partials (deterministic)
        float s = 0.f, m = -3.4e38f;
        for (int i = tid; i < NBP; i += 256) { s += psum[i]; m = fmaxf(m, pmax[i]); }
        ss[tid] = s; sm[tid] = m;
        __syncthreads();
        for (int off = 128; off > 0; off >>= 1) {
            if (tid < off) { ss[tid] += ss[tid + off]; sm[tid] = fmaxf(sm[tid], sm[tid + off]); }
            __syncthreads();
        }
        if (tid == 0) {
            float avg = ss[0] / 266256.f;
            float a = caw1[0], b = caw2[0];
            float z = b * fmaxf(a * avg, 0.f) + b * fmaxf(a * sm[0], 0.f);
            ssc = 1.f / (1.f + expf(-z));
        }
        __syncthreads();
    }
    float sc = ssc;

    int tx0 = (blockIdx.x & 31) * 16, ty0 = (blockIdx.x >> 5) * 16;

    // f12 tile 18x18 (1-halo); OOB entries = 0 (matches c9a zero-pad)
    for (int idx = tid; idx < 324; idx += 256) {
        int r = idx / 18, c = idx - 18 * r;
        int fy = ty0 - 1 + r, fx = tx0 - 1 + c;
        float val = 0.f;
        if (fy >= 0 && fy < 511 && fx >= 0 && fx < 511) {
            float a6 = 0.f;
#pragma unroll
            for (int ky = 0; ky < 6; ++ky) {
                const float* row = hfb + (fy + ky) * 516 + fx;
#pragma unroll
                for (int kx = 0; kx < 6; ++kx) a6 = fmaf(row[kx], w_cat[ky * 6 + kx], a6);
            }
            val = tmp12[fy * 511 + fx] + fmaxf(sc * a6 + b_cat[0], 0.f);
        }
        f12T[r][c] = val;
    }
    __syncthreads();

    int lr = tid >> 4, lc = tid & 15;
    int oy = ty0 + lr, ox = tx0 + lc;
    if (oy >= 511 || ox >= 511) return;

    float hv[9];
#pragma unroll
    for (int ky = 0; ky < 3; ++ky)
#pragma unroll
        for (int kx = 0; kx < 3; ++kx)
            hv[ky * 3 + kx] = f12T[lr + ky][lc + kx];

    float acc[32];
#pragma unroll
    for (int o = 0; o < 32; ++o) acc[o] = bias9a[o];
#pragma unroll
    for (int k = 0; k < 9; ++k) {
        float v = hv[k];
#pragma unroll
        for (int o = 0; o < 32; ++o) acc[o] = fmaf(v, w_c9a[o * 9 + k], acc[o]);
    }
    unsigned short o16[32];
#pragma unroll
    for (int o = 0; o < 32; ++o) o16[o] = f2bf(fmaxf(acc[o], 0.f));
    size_t px = (size_t)(oy + 1) * WPX + (ox + 1);
#pragma unroll
    for (int i = 0; i < 4; ++i)
        *reinterpret_cast<short8*>(h2 + (size_t)i * PSTR + px * 8) =
            reinterpret_cast<const short8*>(o16)[i];
}

// ---------------- K4: 3x3 conv 32->64, MFMA, LDS weights, 2-ahead pipeline --
__global__ __launch_bounds__(256, 3) void k_c9b(const unsigned short* __restrict__ h2,
                                                const unsigned short* __restrict__ wb2,
                                                const float* __restrict__ bias,
                                                float* __restrict__ out)
{
    __shared__ unsigned short swu[9 * 2048];

    int bid = blockIdx.x;
    int xcd = bid & 7, jj = bid >> 3;
    const int q = 127, r = 6;
    int wg = (xcd < r ? xcd * (q + 1) : r * (q + 1) + (xcd - r) * q) + jj;

    int lane = threadIdx.x & 63;
    int wave = threadIdx.x >> 6;
    int y  = wg >> 1;
    int xh = wg & 1;
    int xb = xh * 256 + wave * 64;
    int lpx = lane & 15, kg = lane >> 4;

    {
        const short8* wsrc = reinterpret_cast<const short8*>(wb2);
        short8* wdst = reinterpret_cast<short8*>(swu);
        for (int d = threadIdx.x; d < 2304; d += 256) {
            int kt = d >> 8, rem = d & 255, m = rem >> 6, l = rem & 63;
            wdst[d] = wsrc[kt * 256 + (m * 16 + (l & 15)) * 4 + (l >> 4)];
        }
    }
    __syncthreads();

    f32x4 acc[4][4];
#pragma unroll
    for (int m = 0; m < 4; ++m)
#pragma unroll
        for (int n = 0; n < 4; ++n) acc[m][n] = (f32x4){0.f, 0.f, 0.f, 0.f};

    const unsigned short* hb = h2 + (size_t)kg * PSTR;
    const int base_px = (y + 1) * WPX + (xb + 1) + lpx;
    const int rowm = base_px - WPX, row0 = base_px, rowp = base_px + WPX;
    const short8* swv = reinterpret_cast<const short8*>(swu);

#define LOADB(BUF, ROW, DX) do { \
        const unsigned short* rp = hb + (size_t)((ROW) + (DX)) * 8; \
        BUF[0] = *reinterpret_cast<const short8*>(rp); \
        BUF[1] = *reinterpret_cast<const short8*>(rp + 128); \
        BUF[2] = *reinterpret_cast<const short8*>(rp + 256); \
        BUF[3] = *reinterpret_cast<const short8*>(rp + 384); \
    } while (0)

#define TAP(KT, BUF) do { \
        const short8* ap = swv + (KT) * 256 + lane; \
        short8 a0 = ap[0], a1 = ap[64], a2 = ap[128], a3 = ap[192]; \
        _Pragma("unroll") \
        for (int n = 0; n < 4; ++n) { \
            acc[0][n] = __builtin_amdgcn_mfma_f32_16x16x32_bf16(a0, BUF[n], acc[0][n], 0, 0, 0); \
            acc[1][n] = __builtin_amdgcn_mfma_f32_16x16x32_bf16(a1, BUF[n], acc[1][n], 0, 0, 0); \
            acc[2][n] = __builtin_amdgcn_mfma_f32_16x16x32_bf16(a2, BUF[n], acc[2][n], 0, 0, 0); \
            acc[3][n] = __builtin_amdgcn_mfma_f32_16x16x32_bf16(a3, BUF[n], acc[3][n], 0, 0, 0); \
        } \
    } while (0)

    short8 bX[4], bY[4], bZ[4];
    LOADB(bX, rowm, -1);
    LOADB(bY, rowm,  0);
    LOADB(bZ, rowm, +1); TAP(0, bX);
    LOADB(bX, row0, -1); TAP(1, bY);
    LOADB(bY, row0,  0); TAP(2, bZ);
    LOADB(bZ, row0, +1); TAP(3, bX);
    LOADB(bX, rowp, -1); TAP(4, bY);
    LOADB(bY, rowp,  0); TAP(5, bZ);
    LOADB(bZ, rowp, +1); TAP(6, bX);
    TAP(7, bY);
    TAP(8, bZ);
#undef LOADB
#undef TAP

    const int ybase = y * 511;
#pragma unroll
    for (int m = 0; m < 4; ++m) {
#pragma unroll
        for (int rr = 0; rr < 4; ++rr) {
            int o = m * 16 + kg * 4 + rr;
            float bo = bias[o];
#pragma unroll
            for (int n = 0; n < 4; ++n) {
                int px = xb + n * 16 + lpx;
                if (px < 511)
                    out[(size_t)o * NP + ybase + px] = fmaxf(acc[m][n][rr] + bo, 0.f);
            }
        }
    }
}

// ---------------------------------------------------------------------------
extern "C" void kernel_launch(void* const* d_in, const int* in_sizes, int n_in,
                              void* d_out, int out_size, void* d_ws, size_t ws_size,
                              hipStream_t stream)
{
    (void)in_sizes; (void)n_in; (void)out_size; (void)ws_size;

    const float* x     = (const float*)d_in[0];
    const float* w_x1  = (const float*)d_in[1];
    const float* b_x1  = (const float*)d_in[2];
    const float* w_x2  = (const float*)d_in[3];
    const float* b_x2  = (const float*)d_in[4];
    const float* w_x3  = (const float*)d_in[5];
    const float* b_x3  = (const float*)d_in[6];
    const float* w_hi  = (const float*)d_in[7];
    const float* b_hi  = (const float*)d_in[8];
    const float* ca1w1 = (const float*)d_in[11];
    const float* ca1w2 = (const float*)d_in[12];
    const float* w_cat = (const float*)d_in[15];
    const float* b_cat = (const float*)d_in[16];
    const float* w_c9a = (const float*)d_in[17];
    const float* b_c9a = (const float*)d_in[18];
    const float* w_c9b = (const float*)d_in[19];
    const float* b_c9b = (const float*)d_in[20];

    float* ws    = (float*)d_ws;
    float* tmp12 = ws + 0;                       // 261184
    float* hfb   = ws + 261184;                  // 266304
    float* psum  = ws + 527488;                  // 320
    float* pmax  = ws + 527808;                  // 320
    unsigned short* wb2 = (unsigned short*)(ws + 528128);    // 18432 ushorts
    unsigned short* h2  = (unsigned short*)(ws + 537344);    // 4*PSTR ushorts

    float* out = (float*)d_out;

    double kk[5], ssum = 0.0;
    for (int i = 0; i < 5; ++i) { double r = i - 2.0; kk[i] = exp(-r * r / 0.5); ssum += kk[i]; }
    float g0 = (float)(kk[0] / ssum), g1 = (float)(kk[1] / ssum), g2 = (float)(kk[2] / ssum);

    k_conv123<<<511, 256, 0, stream>>>(x, w_x1, b_x1, w_x2, b_x2, w_x3, b_x3, w_c9b,
                                       tmp12, wb2, h2);
    k_dwtblur<<<NBP, 256, 0, stream>>>(tmp12, w_hi, b_hi, hfb, psum, pmax, g0, g1, g2);
    k_catc9a<<<1024, 256, 0, stream>>>(hfb, tmp12, psum, pmax, ca1w1, ca1w2,
                                       w_cat, b_cat, w_c9a, b_c9a, h2);
    k_c9b<<<1022, 256, 0, stream>>>(h2, wb2, b_c9b, out);
}